// Round 4
// baseline (378.724 us; speedup 1.0000x reference)
//
#include <hip/hip_runtime.h>
#include <math.h>

#define DIM 4096
#define CAP 8192
#define EPS 1e-8f

// ---------------------------------------------------------------------------
// Kernel A: weighted[row] = (dot(mb[row],q) / max(||q||*||mb[row]||, eps))
//                           * importance[row] * exp(-0.001*age[row])
// Wave-per-row: 4 rows per 256-thread block, 2048 blocks. No LDS, no
// __syncthreads — pure shuffle reduction. Mandatory 128 MiB read, BW-bound.
// ---------------------------------------------------------------------------
__global__ __launch_bounds__(256) void score_kernel(
    const float* __restrict__ q,
    const float* __restrict__ mb,
    const float* __restrict__ imp,
    const float* __restrict__ age,
    float* __restrict__ weighted)
{
    const int wave = threadIdx.x >> 6;
    const int lane = threadIdx.x & 63;
    const int row  = (blockIdx.x << 2) + wave;

    const float4* __restrict__ mrow = (const float4*)(mb + (size_t)row * DIM);
    const float4* __restrict__ q4   = (const float4*)q;

    float dot = 0.f, msq = 0.f, qsq = 0.f;
    #pragma unroll 4
    for (int i = lane; i < DIM / 4; i += 64) {
        float4 m  = mrow[i];
        float4 qq = q4[i];
        dot = fmaf(m.w, qq.w, fmaf(m.z, qq.z, fmaf(m.y, qq.y, fmaf(m.x, qq.x, dot))));
        msq = fmaf(m.w, m.w,  fmaf(m.z, m.z,  fmaf(m.y, m.y,  fmaf(m.x, m.x,  msq))));
        qsq = fmaf(qq.w, qq.w, fmaf(qq.z, qq.z, fmaf(qq.y, qq.y, fmaf(qq.x, qq.x, qsq))));
    }
    #pragma unroll
    for (int off = 32; off > 0; off >>= 1) {
        dot += __shfl_down(dot, off, 64);
        msq += __shfl_down(msq, off, 64);
        qsq += __shfl_down(qsq, off, 64);
    }
    if (lane == 0) {
        float denom = fmaxf(sqrtf(qsq) * sqrtf(msq), EPS);
        weighted[row] = (dot / denom) * imp[row] * expf(-0.001f * age[row]);
    }
}

// ---------------------------------------------------------------------------
// Kernel B (fused, overlapped): per-WAVE redundant top-k (no barriers in the
// selection loop) so the W_dec row prefetch — issued into registers right
// after the wv fill barrier — streams from HBM *underneath* the selection.
// Selection touches only LDS/shuffles (lgkmcnt), never vmcnt, so the 16
// in-flight W loads are not drained until the mean-pool consumes globals.
//
// Ownership (per wave, covering all CAP): lane l owns float4s wv4[l + 64*t],
// t=0..31, i.e. elements g = 4l + 256t + c. Ascending (t,c) = ascending g,
// so strict > keeps the lowest index within a lane; the butterfly comparator
// tie-breaks on global index across lanes. Removal = 128-bit register
// bitmask (bit jp = 4t+c) + owner-lane rescan. Matches jax.lax.top_k.
// ---------------------------------------------------------------------------
__global__ __launch_bounds__(256) void topk_decode_kernel(
    const float* __restrict__ weighted,
    const float* __restrict__ mb,
    const int* __restrict__ topk_ptr,
    const float* __restrict__ W,
    const float* __restrict__ b,
    float* __restrict__ out)
{
    __shared__ float wv[CAP];          // 32 KiB, read-only after fill
    __shared__ float rbar[DIM];        // 16 KiB mean-pooled row
    __shared__ int   sidx[4][64];      // per-wave selected indices

    const int tid  = threadIdx.x;
    const int wave = tid >> 6;
    const int lane = tid & 63;

    // load k FIRST so its consume cannot drain the W prefetch queue
    int k = *topk_ptr;
    if (k < 1) k = 1;
    if (k > 64) k = 64;

    // ---- cooperative fill of wv (weighted is L2-hot, 32 KiB) ----
    {
        const float4* __restrict__ w4  = (const float4*)weighted;
        float4* __restrict__       wv4 = (float4*)wv;
        #pragma unroll
        for (int i = tid; i < CAP / 4; i += 256) wv4[i] = w4[i];
    }
    __syncthreads();

    // ---- issue W row prefetch: 16 coalesced float4 per lane, kept live ----
    const int j = (blockIdx.x << 2) + wave;
    const float4* __restrict__ wrow4 = (const float4*)(W + (size_t)j * DIM);
    float4 wreg[16];
    #pragma unroll
    for (int t = 0; t < 16; ++t) wreg[t] = wrow4[lane + (t << 6)];

    // ---- per-wave top-k, barrier-free ----
    const float4* __restrict__ wv4 = (const float4*)wv;
    unsigned long long cons0 = 0ULL, cons1 = 0ULL;   // consumed bits jp=4t+c

    float bv; int bi;
    // masked rescan of this lane's 32 float4 candidates
    auto rescan = [&]() {
        bv = -INFINITY; bi = 0x7fffffff;
        #pragma unroll
        for (int t = 0; t < 32; ++t) {
            const float4 v = wv4[lane + (t << 6)];
            const int base = (lane << 2) + (t << 8);
            const unsigned long long m = (t < 16) ? cons0 : cons1;
            const int sh = (t & 15) << 2;
            if (!((m >> (sh + 0)) & 1ULL) && v.x > bv) { bv = v.x; bi = base + 0; }
            if (!((m >> (sh + 1)) & 1ULL) && v.y > bv) { bv = v.y; bi = base + 1; }
            if (!((m >> (sh + 2)) & 1ULL) && v.z > bv) { bv = v.z; bi = base + 2; }
            if (!((m >> (sh + 3)) & 1ULL) && v.w > bv) { bv = v.w; bi = base + 3; }
        }
    };
    rescan();   // initial scan (empty mask)

    for (int it = 0; it < k; ++it) {
        // butterfly argmax: all 64 lanes converge to (cv,ci)
        float cv = bv; int ci = bi;
        #pragma unroll
        for (int off = 32; off > 0; off >>= 1) {
            float ov = __shfl_xor(cv, off, 64);
            int   oi = __shfl_xor(ci, off, 64);
            if (ov > cv || (ov == cv && oi < ci)) { cv = ov; ci = oi; }
        }
        if (lane == 0) sidx[wave][it] = ci;
        if (((ci >> 2) & 63) == lane) {          // owner removes + rescans
            const int jp = ((ci >> 8) << 2) | (ci & 3);
            if (jp < 64) cons0 |= 1ULL << jp;
            else         cons1 |= 1ULL << (jp - 64);
            rescan();
        }
    }
    __builtin_amdgcn_wave_barrier();   // order sidx writes vs same-wave reads

    // ---- mean-pool: wave w covers columns [w*1024, (w+1)*1024) ----
    float4 racc[4];
    #pragma unroll
    for (int t = 0; t < 4; ++t) racc[t] = make_float4(0.f, 0.f, 0.f, 0.f);
    for (int r = 0; r < k; ++r) {
        const int idx = sidx[wave][r];
        const float4* __restrict__ mrow4 = (const float4*)(mb + (size_t)idx * DIM);
        #pragma unroll
        for (int t = 0; t < 4; ++t) {
            const float4 v = mrow4[(wave << 8) + (t << 6) + lane];
            racc[t].x += v.x; racc[t].y += v.y; racc[t].z += v.z; racc[t].w += v.w;
        }
    }
    const float inv_k = 1.0f / (float)k;
    float4* __restrict__ rbar4 = (float4*)rbar;
    #pragma unroll
    for (int t = 0; t < 4; ++t) {
        racc[t].x *= inv_k; racc[t].y *= inv_k;
        racc[t].z *= inv_k; racc[t].w *= inv_k;
        rbar4[(wave << 8) + (t << 6) + lane] = racc[t];
    }
    __syncthreads();

    // ---- decode: dot(W[j,:], rbar) from registers + LDS ----
    float acc = 0.f;
    #pragma unroll
    for (int t = 0; t < 16; ++t) {
        const float4 w = wreg[t];
        const float4 v = rbar4[lane + (t << 6)];
        acc = fmaf(w.w, v.w, fmaf(w.z, v.z, fmaf(w.y, v.y, fmaf(w.x, v.x, acc))));
    }
    #pragma unroll
    for (int off = 32; off > 0; off >>= 1) acc += __shfl_down(acc, off, 64);
    if (lane == 0) out[j] = acc + b[j];
}

extern "C" void kernel_launch(void* const* d_in, const int* in_sizes, int n_in,
                              void* d_out, int out_size, void* d_ws, size_t ws_size,
                              hipStream_t stream) {
    const float* query      = (const float*)d_in[0];
    const float* memory     = (const float*)d_in[1];
    const float* importance = (const float*)d_in[2];
    const float* age        = (const float*)d_in[3];
    const float* W_dec      = (const float*)d_in[4];
    const float* b_dec      = (const float*)d_in[5];
    const int*   top_k      = (const int*)d_in[6];

    float* weighted = (float*)d_ws;                  // CAP floats
    float* out      = (float*)d_out;

    score_kernel<<<CAP / 4, 256, 0, stream>>>(query, memory, importance, age, weighted);
    topk_decode_kernel<<<DIM / 4, 256, 0, stream>>>(weighted, memory, top_k,
                                                    W_dec, b_dec, out);
}

// Round 7
// 257.196 us; speedup vs baseline: 1.4725x; 1.4725x over previous
//
#include <hip/hip_runtime.h>
#include <math.h>

#define DIM 4096
#define CAP 8192
#define EPS 1e-8f

// ---------------------------------------------------------------------------
// Kernel A: weighted[row] = (dot(mb[row],q) / max(||q||*||mb[row]||, eps))
//                           * importance[row] * exp(-0.001*age[row])
// Wave-per-row: 4 rows per 256-thread block, 2048 blocks. No LDS, no
// __syncthreads — pure shuffle reduction. Mandatory 128 MiB read, BW-bound
// (floor ~20.4 µs @ 6.3 TB/s).
// ---------------------------------------------------------------------------
__global__ __launch_bounds__(256) void score_kernel(
    const float* __restrict__ q,
    const float* __restrict__ mb,
    const float* __restrict__ imp,
    const float* __restrict__ age,
    float* __restrict__ weighted)
{
    const int wave = threadIdx.x >> 6;
    const int lane = threadIdx.x & 63;
    const int row  = (blockIdx.x << 2) + wave;

    const float4* __restrict__ mrow = (const float4*)(mb + (size_t)row * DIM);
    const float4* __restrict__ q4   = (const float4*)q;

    float dot = 0.f, msq = 0.f, qsq = 0.f;
    #pragma unroll 4
    for (int i = lane; i < DIM / 4; i += 64) {
        float4 m  = mrow[i];
        float4 qq = q4[i];
        dot = fmaf(m.w, qq.w, fmaf(m.z, qq.z, fmaf(m.y, qq.y, fmaf(m.x, qq.x, dot))));
        msq = fmaf(m.w, m.w,  fmaf(m.z, m.z,  fmaf(m.y, m.y,  fmaf(m.x, m.x,  msq))));
        qsq = fmaf(qq.w, qq.w, fmaf(qq.z, qq.z, fmaf(qq.y, qq.y, fmaf(qq.x, qq.x, qsq))));
    }
    #pragma unroll
    for (int off = 32; off > 0; off >>= 1) {
        dot += __shfl_down(dot, off, 64);
        msq += __shfl_down(msq, off, 64);
        qsq += __shfl_down(qsq, off, 64);
    }
    if (lane == 0) {
        float denom = fmaxf(sqrtf(qsq) * sqrtf(msq), EPS);
        weighted[row] = (dot / denom) * imp[row] * expf(-0.001f * age[row]);
    }
}

// ---------------------------------------------------------------------------
// Kernel B (fused; R3 structure restored): block-wide redundant top-k with
// candidates register-resident across 256 threads, + mean-pool into LDS,
// + decode of 4 outputs per block. 1024 blocks x 256 threads.
//
// One change vs R3: the W_dec row prefetch (16 float4/lane into registers)
// is issued AFTER the selection loop and BEFORE the mean-pool's mb gathers,
// so the dominant 64 MiB W stream overlaps the L3-hot gather instead of
// starting after it (vmcnt retires in issue order).
//
// Ownership: thread t owns elements {j*1024 + t*4 + c : j=0..7, c=0..3},
// loaded as 8 coalesced float4 (w4[j*256 + t]). Removal/rescan use only
// compile-time register indices. Lowest-index tie-break on the GLOBAL index
// matches jax.lax.top_k.
// ---------------------------------------------------------------------------
__global__ __launch_bounds__(256) void topk_decode_kernel(
    const float* __restrict__ weighted,
    const float* __restrict__ mb,
    const int* __restrict__ topk_ptr,
    const float* __restrict__ W,
    const float* __restrict__ b,
    float* __restrict__ out)
{
    __shared__ float rbar[DIM];        // 16 KiB mean-pooled row
    __shared__ float rv[4];
    __shared__ int   ri[4];
    __shared__ int   sidx[64];

    const int tid  = threadIdx.x;
    const int wave = tid >> 6;
    const int lane = tid & 63;

    int k = *topk_ptr;
    if (k < 1) k = 1;
    if (k > 64) k = 64;

    // ---- load 32 candidates per thread into registers (coalesced) ----
    const float4* __restrict__ w4 = (const float4*)weighted;
    float4 val[8];
    #pragma unroll
    for (int j = 0; j < 8; ++j) val[j] = w4[(j << 8) + tid];

    // ---- initial per-thread argmax (ascending global index, strict >) ----
    float bv = -INFINITY; int bi = 0x7fffffff;
    #pragma unroll
    for (int j = 0; j < 8; ++j) {
        const int base = (j << 10) + (tid << 2);
        if (val[j].x > bv) { bv = val[j].x; bi = base + 0; }
        if (val[j].y > bv) { bv = val[j].y; bi = base + 1; }
        if (val[j].z > bv) { bv = val[j].z; bi = base + 2; }
        if (val[j].w > bv) { bv = val[j].w; bi = base + 3; }
    }

    for (int it = 0; it < k; ++it) {
        // wave shuffle argmax with global-index tie-break
        float cv = bv; int ci = bi;
        #pragma unroll
        for (int off = 32; off > 0; off >>= 1) {
            float ov = __shfl_down(cv, off, 64);
            int   oi = __shfl_down(ci, off, 64);
            if (ov > cv || (ov == cv && oi < ci)) { cv = ov; ci = oi; }
        }
        if (lane == 0) { rv[wave] = cv; ri[wave] = ci; }
        __syncthreads();
        if (tid == 0) {
            float best = rv[0]; int besti = ri[0];
            #pragma unroll
            for (int w = 1; w < 4; ++w) {
                if (rv[w] > best || (rv[w] == best && ri[w] < besti)) {
                    best = rv[w]; besti = ri[w];
                }
            }
            sidx[it] = besti;
        }
        __syncthreads();
        const int gbi = sidx[it];
        // owner removes the selected element and rescans its 32 registers
        if (((gbi >> 2) & 255) == tid) {
            const int jr = gbi >> 10;
            const int cr = gbi & 3;
            #pragma unroll
            for (int j = 0; j < 8; ++j) {
                if (j == jr) {
                    if (cr == 0) val[j].x = -INFINITY;
                    if (cr == 1) val[j].y = -INFINITY;
                    if (cr == 2) val[j].z = -INFINITY;
                    if (cr == 3) val[j].w = -INFINITY;
                }
            }
            bv = -INFINITY; bi = 0x7fffffff;
            #pragma unroll
            for (int j = 0; j < 8; ++j) {
                const int base = (j << 10) + (tid << 2);
                if (val[j].x > bv) { bv = val[j].x; bi = base + 0; }
                if (val[j].y > bv) { bv = val[j].y; bi = base + 1; }
                if (val[j].z > bv) { bv = val[j].z; bi = base + 2; }
                if (val[j].w > bv) { bv = val[j].w; bi = base + 3; }
            }
        }
        // wave lockstep orders the rescan before next iteration's shuffles;
        // cross-wave flow goes through rv/ri + __syncthreads.
    }
    __syncthreads();

    // ---- issue W row prefetch NOW: overlaps the mean-pool's mb gathers ----
    const int j = (blockIdx.x << 2) + wave;
    const float4* __restrict__ wrow4 = (const float4*)(W + (size_t)j * DIM);
    float4 wreg[16];
    #pragma unroll
    for (int t = 0; t < 16; ++t) wreg[t] = wrow4[lane + (t << 6)];

    // ---- mean-pool the k selected rows into LDS (rows are L3-broadcast) ----
    const float inv_k = 1.0f / (float)k;
    float4* __restrict__ rbar4 = (float4*)rbar;
    for (int i = tid; i < DIM / 4; i += 256) {
        float4 acc = make_float4(0.f, 0.f, 0.f, 0.f);
        for (int r = 0; r < k; ++r) {
            const float4 v = ((const float4*)(mb + (size_t)sidx[r] * DIM))[i];
            acc.x += v.x; acc.y += v.y; acc.z += v.z; acc.w += v.w;
        }
        acc.x *= inv_k; acc.y *= inv_k; acc.z *= inv_k; acc.w *= inv_k;
        rbar4[i] = acc;
    }
    __syncthreads();

    // ---- decode: dot(W[j,:], rbar) from registers + LDS ----
    float acc = 0.f;
    #pragma unroll
    for (int t = 0; t < 16; ++t) {
        const float4 w = wreg[t];
        const float4 v = rbar4[lane + (t << 6)];
        acc = fmaf(w.w, v.w, fmaf(w.z, v.z, fmaf(w.y, v.y, fmaf(w.x, v.x, acc))));
    }
    #pragma unroll
    for (int off = 32; off > 0; off >>= 1) acc += __shfl_down(acc, off, 64);
    if (lane == 0) out[j] = acc + b[j];
}

extern "C" void kernel_launch(void* const* d_in, const int* in_sizes, int n_in,
                              void* d_out, int out_size, void* d_ws, size_t ws_size,
                              hipStream_t stream) {
    const float* query      = (const float*)d_in[0];
    const float* memory     = (const float*)d_in[1];
    const float* importance = (const float*)d_in[2];
    const float* age        = (const float*)d_in[3];
    const float* W_dec      = (const float*)d_in[4];
    const float* b_dec      = (const float*)d_in[5];
    const int*   top_k      = (const int*)d_in[6];

    float* weighted = (float*)d_ws;                  // CAP floats
    float* out      = (float*)d_out;

    score_kernel<<<CAP / 4, 256, 0, stream>>>(query, memory, importance, age, weighted);
    topk_decode_kernel<<<DIM / 4, 256, 0, stream>>>(weighted, memory, top_k,
                                                    W_dec, b_dec, out);
}